// Round 1
// baseline (196.440 us; speedup 1.0000x reference)
//
#include <hip/hip_runtime.h>

#define DD 256   // feature dim
#define N1 512
#define N2 512
#define BB 4

// ---------------------------------------------------------------------------
// Kernel 1: projection GEMMs.
//   which==0: xp = x @ W1[:256]  + b1      (M=2048, N=256, K=256)
//   which==1: yp = y @ W1[256:]            (M=2048, N=256, K=256)
// 64x64 tile per 256-thread block, 4x4 register blocking, K-chunks of 16.
// ---------------------------------------------------------------------------
__global__ __launch_bounds__(256) void proj_kernel(
    const float* __restrict__ x, const float* __restrict__ y,
    const float* __restrict__ W1, const float* __restrict__ b1,
    float* __restrict__ xp, float* __restrict__ yp)
{
    const int which = blockIdx.z;
    const float* __restrict__ A  = which ? y : x;
    const float* __restrict__ Bw = W1 + which * DD * DD;
    float* __restrict__ outp = which ? yp : xp;

    __shared__ float As[16][68];   // A^T tile: As[k][m], pad 68 for banks
    __shared__ float Bs[16][68];   // B tile:   Bs[k][n]

    const int tid = threadIdx.x;
    const int tx = tid & 15, ty = tid >> 4;
    const int mBase = blockIdx.x * 64;
    const int nBase = blockIdx.y * 64;

    float acc[4][4] = {};

    const float4* A4 = (const float4*)A;
    const float4* B4 = (const float4*)Bw;

    for (int kc = 0; kc < 16; ++kc) {
        {   // stage A tile (64 rows x 16 k), transposed into As[k][m]
            int r = tid >> 2;         // 0..63
            int c = tid & 3;          // float4 index within k-chunk
            float4 av = A4[(mBase + r) * (DD/4) + kc*4 + c];
            As[c*4+0][r] = av.x;
            As[c*4+1][r] = av.y;
            As[c*4+2][r] = av.z;
            As[c*4+3][r] = av.w;
        }
        {   // stage B tile (16 k x 64 cols)
            int r = tid >> 4;         // 0..15
            int c = tid & 15;         // 0..15
            float4 bv = B4[(kc*16 + r) * (DD/4) + (nBase>>2) + c];
            *(float4*)&Bs[r][c*4] = bv;
        }
        __syncthreads();
        #pragma unroll
        for (int k = 0; k < 16; ++k) {
            float4 a = *(const float4*)&As[k][ty*4];
            float4 b = *(const float4*)&Bs[k][tx*4];
            float av[4] = {a.x, a.y, a.z, a.w};
            float bv[4] = {b.x, b.y, b.z, b.w};
            #pragma unroll
            for (int i = 0; i < 4; ++i)
                #pragma unroll
                for (int j = 0; j < 4; ++j)
                    acc[i][j] = fmaf(av[i], bv[j], acc[i][j]);
        }
        __syncthreads();
    }

    float4 bias = make_float4(0.f, 0.f, 0.f, 0.f);
    if (which == 0) bias = *((const float4*)b1 + (nBase>>2) + tx);
    #pragma unroll
    for (int i = 0; i < 4; ++i) {
        float4 o;
        o.x = acc[i][0] + bias.x;
        o.y = acc[i][1] + bias.y;
        o.z = acc[i][2] + bias.z;
        o.w = acc[i][3] + bias.w;
        ((float4*)outp)[(mBase + ty*4 + i) * (DD/4) + (nBase>>2) + tx] = o;
    }
}

// ---------------------------------------------------------------------------
// Exact-gelu (Abramowitz–Stegun 7.1.26 erf, |err| <= 1.5e-7) fused with the
// W2 dot-product FMA.  ~17 VALU ops/element incl. v_rcp_f32 + v_exp_f32.
// Phi(h) = 0.5*(1+erf(h/sqrt(2)));  q = 0.5*poly(t)*exp(-h^2/2)
// ---------------------------------------------------------------------------
__device__ __forceinline__ float gelu_fma(float h, float w, float acc)
{
    const float kA1 =  0.5f *  0.254829592f;
    const float kA2 =  0.5f * -0.284496736f;
    const float kA3 =  0.5f *  1.421413741f;
    const float kA4 =  0.5f * -1.453152027f;
    const float kA5 =  0.5f *  1.061405429f;
    float z = fabsf(h) * 0.70710678118f;
    float t = __builtin_amdgcn_rcpf(fmaf(0.3275911f, z, 1.0f));
    float p = t * fmaf(t, fmaf(t, fmaf(t, fmaf(t, kA5, kA4), kA3), kA2), kA1);
    float q = p * __builtin_amdgcn_exp2f(h * h * -0.7213475204f); // exp(-h^2/2)
    float phi = (h >= 0.0f) ? (1.0f - q) : q;
    return fmaf(h * phi, w, acc);
}

// ---------------------------------------------------------------------------
// Kernel 2: o[b,n,m] = sum_d gelu(xp[b,n,d] + yp[b,m,d]) * W2[d] + b2
// 32x32 (n,m) tile per block; full 256-d panels in LDS (64 KB total) with a
// float4-rotation swizzle so all compute reads are conflict-free b128s.
// Each thread: 2x2 outputs with stride-16 blocking.
// ---------------------------------------------------------------------------
__global__ __launch_bounds__(256) void cross_kernel(
    const float* __restrict__ xp, const float* __restrict__ yp,
    const float* __restrict__ W2, const float* __restrict__ b2,
    float* __restrict__ o)
{
    __shared__ float xs[32 * 256];
    __shared__ float ys[32 * 256];

    const int tid   = threadIdx.x;
    const int b     = blockIdx.z;
    const int mBase = blockIdx.x * 32;
    const int nBase = blockIdx.y * 32;

    const float4* xp4 = (const float4*)(xp + (b * N1 + nBase) * DD);
    const float4* yp4 = (const float4*)(yp + (b * N2 + mBase) * DD);

    // stage 32x256 panels; swizzle: (row, c4) -> row*256 + ((c4+row)&63)*4
    #pragma unroll
    for (int i = 0; i < 8; ++i) {
        int idx = tid + i * 256;       // 0..2047
        int row = idx >> 6;            // 0..31
        int c4  = idx & 63;            // float4 column
        float4 v = xp4[row * 64 + c4];
        *(float4*)&xs[row * 256 + (((c4 + row) & 63) << 2)] = v;
        float4 w = yp4[row * 64 + c4];
        *(float4*)&ys[row * 256 + (((c4 + row) & 63) << 2)] = w;
    }
    __syncthreads();

    const int tx = tid & 15, ty = tid >> 4;
    const int r0 = ty, r1 = ty + 16;   // n within tile
    const int c0 = tx, c1 = tx + 16;   // m within tile

    float acc00 = 0.f, acc01 = 0.f, acc10 = 0.f, acc11 = 0.f;

    const float4* __restrict__ W2v = (const float4*)W2;

    #pragma unroll 4
    for (int c = 0; c < 64; ++c) {
        float4 wv = W2v[c];            // uniform -> scalar load
        float4 xa = *(const float4*)&xs[r0 * 256 + (((c + r0) & 63) << 2)];
        float4 xb = *(const float4*)&xs[r1 * 256 + (((c + r1) & 63) << 2)];
        float4 ya = *(const float4*)&ys[c0 * 256 + (((c + c0) & 63) << 2)];
        float4 yb = *(const float4*)&ys[c1 * 256 + (((c + c1) & 63) << 2)];
        float xav[4] = {xa.x, xa.y, xa.z, xa.w};
        float xbv[4] = {xb.x, xb.y, xb.z, xb.w};
        float yav[4] = {ya.x, ya.y, ya.z, ya.w};
        float ybv[4] = {yb.x, yb.y, yb.z, yb.w};
        float wvv[4] = {wv.x, wv.y, wv.z, wv.w};
        #pragma unroll
        for (int j = 0; j < 4; ++j) {
            acc00 = gelu_fma(xav[j] + yav[j], wvv[j], acc00);
            acc01 = gelu_fma(xav[j] + ybv[j], wvv[j], acc01);
            acc10 = gelu_fma(xbv[j] + yav[j], wvv[j], acc10);
            acc11 = gelu_fma(xbv[j] + ybv[j], wvv[j], acc11);
        }
    }

    const float bias2 = b2[0];
    float* __restrict__ obase = o + ((size_t)(b * N1 + nBase) * N2) + mBase;
    obase[r0 * N2 + c0] = acc00 + bias2;
    obase[r0 * N2 + c1] = acc01 + bias2;
    obase[r1 * N2 + c0] = acc10 + bias2;
    obase[r1 * N2 + c1] = acc11 + bias2;
}

extern "C" void kernel_launch(void* const* d_in, const int* in_sizes, int n_in,
                              void* d_out, int out_size, void* d_ws, size_t ws_size,
                              hipStream_t stream)
{
    const float* x  = (const float*)d_in[0];
    const float* y  = (const float*)d_in[1];
    const float* W1 = (const float*)d_in[2];
    const float* b1 = (const float*)d_in[3];
    const float* W2 = (const float*)d_in[4];
    const float* b2 = (const float*)d_in[5];
    float* o  = (float*)d_out;
    float* xp = (float*)d_ws;                 // 2048*256 floats = 2 MB
    float* yp = xp + (BB * N1) * DD;          // next 2 MB

    dim3 g1(32, 4, 2);        // (M/64, N/64, which)
    proj_kernel<<<g1, 256, 0, stream>>>(x, y, W1, b1, xp, yp);

    dim3 g2(N2 / 32, N1 / 32, BB);
    cross_kernel<<<g2, 256, 0, stream>>>(xp, yp, W2, b2, o);
}

// Round 2
// 172.933 us; speedup vs baseline: 1.1359x; 1.1359x over previous
//
#include <hip/hip_runtime.h>

#define DD 256   // feature dim
#define N1 512
#define N2 512
#define BB 4

// ---------------------------------------------------------------------------
// Kernel 1: projection GEMMs (fp32 vector ALU; no fp32 MFMA on CDNA4).
//   which==0: xp = x @ W1[:256]  + b1      (M=2048, N=256, K=256)
//   which==1: yp = y @ W1[256:]            (M=2048, N=256, K=256)
// 64x64 tile / 256 threads / 4x4 register blocking. K-chunks of 32 with
// register-prefetch double buffering (global->reg for chunk k+1 issued
// before compute of chunk k) to hide staging latency at 1 block/CU.
// ---------------------------------------------------------------------------
__global__ __launch_bounds__(256) void proj_kernel(
    const float* __restrict__ x, const float* __restrict__ y,
    const float* __restrict__ W1, const float* __restrict__ b1,
    float* __restrict__ xp, float* __restrict__ yp)
{
    const int which = blockIdx.z;
    const float* __restrict__ A  = which ? y : x;
    const float* __restrict__ Bw = W1 + which * DD * DD;
    float* __restrict__ outp = which ? yp : xp;

    __shared__ float As[32 * 68];   // As[k][m] (transposed), row stride 68
    __shared__ float Bs[32 * 68];   // Bs[k][n], row stride 68

    const int tid = threadIdx.x;
    const int tx = tid & 15, ty = tid >> 4;
    const int mBase = blockIdx.x * 64;
    const int nBase = blockIdx.y * 64;

    const float4* A4 = (const float4*)A;
    const float4* B4 = (const float4*)Bw;

    // staging index split: A: 64 rows x 8 float4/chunk; B: 32 k x 16 float4
    const int ar = tid >> 2;       // 0..63  A row
    const int ac = tid & 3;        // 0..3   A float4 col (and +4)
    const int br = tid >> 4;       // 0..15  B k-row (and +16)
    const int bc = tid & 15;       // 0..15  B float4 col

    float4 pa0, pa1, pb0, pb1;

    // prefetch chunk 0
    pa0 = A4[(mBase + ar) * 64 + 0 * 8 + ac];
    pa1 = A4[(mBase + ar) * 64 + 0 * 8 + ac + 4];
    pb0 = B4[(0 * 32 + br) * 64 + (nBase >> 2) + bc];
    pb1 = B4[(0 * 32 + br + 16) * 64 + (nBase >> 2) + bc];

    float acc[4][4] = {};

    for (int kc = 0; kc < 8; ++kc) {
        __syncthreads();   // previous chunk's reads done
        {   // regs -> LDS (A transposed)
            float av0[4] = {pa0.x, pa0.y, pa0.z, pa0.w};
            float av1[4] = {pa1.x, pa1.y, pa1.z, pa1.w};
            #pragma unroll
            for (int q = 0; q < 4; ++q) As[(ac * 4 + q) * 68 + ar] = av0[q];
            #pragma unroll
            for (int q = 0; q < 4; ++q) As[((ac + 4) * 4 + q) * 68 + ar] = av1[q];
            *(float4*)&Bs[br * 68 + bc * 4] = pb0;
            *(float4*)&Bs[(br + 16) * 68 + bc * 4] = pb1;
        }
        __syncthreads();
        if (kc < 7) {   // prefetch next chunk; waitcnt lands at next stage
            pa0 = A4[(mBase + ar) * 64 + (kc + 1) * 8 + ac];
            pa1 = A4[(mBase + ar) * 64 + (kc + 1) * 8 + ac + 4];
            pb0 = B4[((kc + 1) * 32 + br) * 64 + (nBase >> 2) + bc];
            pb1 = B4[((kc + 1) * 32 + br + 16) * 64 + (nBase >> 2) + bc];
        }
        #pragma unroll
        for (int k = 0; k < 32; ++k) {
            float4 a = *(const float4*)&As[k * 68 + ty * 4];
            float4 b = *(const float4*)&Bs[k * 68 + tx * 4];
            float av[4] = {a.x, a.y, a.z, a.w};
            float bv[4] = {b.x, b.y, b.z, b.w};
            #pragma unroll
            for (int i = 0; i < 4; ++i)
                #pragma unroll
                for (int j = 0; j < 4; ++j)
                    acc[i][j] = fmaf(av[i], bv[j], acc[i][j]);
        }
    }

    float4 bias = make_float4(0.f, 0.f, 0.f, 0.f);
    if (which == 0) bias = *((const float4*)b1 + (nBase >> 2) + tx);
    #pragma unroll
    for (int i = 0; i < 4; ++i) {
        float4 o;
        o.x = acc[i][0] + bias.x;
        o.y = acc[i][1] + bias.y;
        o.z = acc[i][2] + bias.z;
        o.w = acc[i][3] + bias.w;
        ((float4*)outp)[(mBase + ty * 4 + i) * (DD / 4) + (nBase >> 2) + tx] = o;
    }
}

// ---------------------------------------------------------------------------
// tanh-form gelu fused with the W2 FMA, folded to minimize VALU ops:
//   gelu(h) = 0.5h(1+tanh(u)), u = 0.79788456(h + 0.044715 h^3)
//           = h * (1 - 1/(e^{2u}+1))
//   e^{2u} = exp2(h * (K1 + K2 h^2)),  K1 = 2*log2(e)*0.79788456 = 2.3022083
//                                      K2 = K1 * 0.044715       = 0.1029432
// 7 full-rate VALU + exp2 + rcp per element. |err| <= ~5e-4 (max near h~3).
// ---------------------------------------------------------------------------
__device__ __forceinline__ float gelu_term(float xv, float yv, float w, float acc)
{
    float h  = xv + yv;
    float h2 = h * h;
    float z  = h * fmaf(h2, 0.1029432f, 2.3022083f);
    float e  = __builtin_amdgcn_exp2f(z);
    float r  = __builtin_amdgcn_rcpf(e + 1.0f);
    float g  = fmaf(-h, r, h);          // h * (1 - r)
    return fmaf(g, w, acc);
}

// ---------------------------------------------------------------------------
// Kernel 2: o[b,n,m] = sum_d gelu(xp[b,n,d] + yp[b,m,d]) * W2[d] + b2
// 32x32 (n,m) tile per 64-thread (single-wave) block, 4x4 outputs/thread.
// d staged in chunks of 64 (17.4 KB LDS -> many blocks/CU; 1024 blocks total
// so every SIMD holds a wave). Row stride 68 floats: hot-loop ds_read_b128
// are conflict-free (8 distinct addrs x 8-lane broadcast per instruction).
// Single-wave workgroup => __syncthreads is effectively free.
// ---------------------------------------------------------------------------
__global__ __launch_bounds__(64) void cross_kernel(
    const float* __restrict__ xp, const float* __restrict__ yp,
    const float* __restrict__ W2, const float* __restrict__ b2,
    float* __restrict__ o)
{
    __shared__ float xs[32 * 68];
    __shared__ float ys[32 * 68];

    const int tid   = threadIdx.x;
    const int b     = blockIdx.z;
    const int mBase = blockIdx.x * 32;
    const int nBase = blockIdx.y * 32;
    const int tx = tid & 7;        // m sub-index
    const int ty = tid >> 3;       // n sub-index

    const float4* xp4 = (const float4*)xp + (b * N1 + nBase) * (DD / 4);
    const float4* yp4 = (const float4*)yp + (b * N2 + mBase) * (DD / 4);
    const float4* __restrict__ W2v = (const float4*)W2;

    float acc[4][4] = {};

    for (int kc = 0; kc < 4; ++kc) {
        __syncthreads();
        #pragma unroll
        for (int t = 0; t < 8; ++t) {
            int idx = tid + t * 64;      // 0..511
            int row = idx >> 4;          // 0..31
            int c4  = idx & 15;          // float4 col in chunk
            *(float4*)&xs[row * 68 + c4 * 4] = xp4[row * 64 + kc * 16 + c4];
            *(float4*)&ys[row * 68 + c4 * 4] = yp4[row * 64 + kc * 16 + c4];
        }
        __syncthreads();

        #pragma unroll
        for (int c4 = 0; c4 < 16; ++c4) {
            float4 wv = W2v[kc * 16 + c4];   // uniform -> scalar load
            float4 xr[4], yr[4];
            #pragma unroll
            for (int i = 0; i < 4; ++i) {
                xr[i] = *(const float4*)&xs[(ty + 8 * i) * 68 + c4 * 4];
                yr[i] = *(const float4*)&ys[(tx + 8 * i) * 68 + c4 * 4];
            }
            #pragma unroll
            for (int i = 0; i < 4; ++i) {
                #pragma unroll
                for (int j = 0; j < 4; ++j) {
                    float a = acc[i][j];
                    a = gelu_term(xr[i].x, yr[j].x, wv.x, a);
                    a = gelu_term(xr[i].y, yr[j].y, wv.y, a);
                    a = gelu_term(xr[i].z, yr[j].z, wv.z, a);
                    a = gelu_term(xr[i].w, yr[j].w, wv.w, a);
                    acc[i][j] = a;
                }
            }
        }
    }

    const float bias2 = b2[0];
    const size_t base = ((size_t)(b * N1 + nBase)) * N2 + mBase;
    #pragma unroll
    for (int i = 0; i < 4; ++i) {
        #pragma unroll
        for (int j = 0; j < 4; ++j) {
            o[base + (size_t)(ty + 8 * i) * N2 + (tx + 8 * j)] = acc[i][j] + bias2;
        }
    }
}

extern "C" void kernel_launch(void* const* d_in, const int* in_sizes, int n_in,
                              void* d_out, int out_size, void* d_ws, size_t ws_size,
                              hipStream_t stream)
{
    const float* x  = (const float*)d_in[0];
    const float* y  = (const float*)d_in[1];
    const float* W1 = (const float*)d_in[2];
    const float* b1 = (const float*)d_in[3];
    const float* W2 = (const float*)d_in[4];
    const float* b2 = (const float*)d_in[5];
    float* o  = (float*)d_out;
    float* xp = (float*)d_ws;                 // 2048*256 floats = 2 MB
    float* yp = xp + (BB * N1) * DD;          // next 2 MB

    dim3 g1(32, 4, 2);          // (M/64, N/64, which)
    proj_kernel<<<g1, 256, 0, stream>>>(x, y, W1, b1, xp, yp);

    dim3 g2(N2 / 32, N1 / 32, BB);   // 16 x 16 x 4 = 1024 single-wave blocks
    cross_kernel<<<g2, 64, 0, stream>>>(xp, yp, W2, b2, o);
}

// Round 3
// 160.123 us; speedup vs baseline: 1.2268x; 1.0800x over previous
//
#include <hip/hip_runtime.h>

#define DD 256   // feature dim
#define N1 512
#define N2 512
#define BB 4

// ---------------------------------------------------------------------------
// Kernel 1: projection GEMMs (fp32 vector ALU; no fp32 MFMA on CDNA4).
//   which==0: xp = x @ W1[:256]  + b1      (M=2048, N=256, K=256)
//   which==1: yp = y @ W1[256:]            (M=2048, N=256, K=256)
// 64x64 tile / 256 threads / 4x4 register blocking, K-chunks of 32 with
// register-prefetch double buffering.
// ---------------------------------------------------------------------------
__global__ __launch_bounds__(256) void proj_kernel(
    const float* __restrict__ x, const float* __restrict__ y,
    const float* __restrict__ W1, const float* __restrict__ b1,
    float* __restrict__ xp, float* __restrict__ yp)
{
    const int which = blockIdx.z;
    const float* __restrict__ A  = which ? y : x;
    const float* __restrict__ Bw = W1 + which * DD * DD;
    float* __restrict__ outp = which ? yp : xp;

    __shared__ float As[32 * 68];   // As[k][m] (transposed), row stride 68
    __shared__ float Bs[32 * 68];   // Bs[k][n], row stride 68

    const int tid = threadIdx.x;
    const int tx = tid & 15, ty = tid >> 4;
    const int mBase = blockIdx.x * 64;
    const int nBase = blockIdx.y * 64;

    const float4* A4 = (const float4*)A;
    const float4* B4 = (const float4*)Bw;

    const int ar = tid >> 2;       // 0..63  A row
    const int ac = tid & 3;        // 0..3   A float4 col (and +4)
    const int br = tid >> 4;       // 0..15  B k-row (and +16)
    const int bc = tid & 15;       // 0..15  B float4 col

    float4 pa0, pa1, pb0, pb1;

    pa0 = A4[(mBase + ar) * 64 + 0 * 8 + ac];
    pa1 = A4[(mBase + ar) * 64 + 0 * 8 + ac + 4];
    pb0 = B4[(0 * 32 + br) * 64 + (nBase >> 2) + bc];
    pb1 = B4[(0 * 32 + br + 16) * 64 + (nBase >> 2) + bc];

    float acc[4][4] = {};

    for (int kc = 0; kc < 8; ++kc) {
        __syncthreads();
        {
            float av0[4] = {pa0.x, pa0.y, pa0.z, pa0.w};
            float av1[4] = {pa1.x, pa1.y, pa1.z, pa1.w};
            #pragma unroll
            for (int q = 0; q < 4; ++q) As[(ac * 4 + q) * 68 + ar] = av0[q];
            #pragma unroll
            for (int q = 0; q < 4; ++q) As[((ac + 4) * 4 + q) * 68 + ar] = av1[q];
            *(float4*)&Bs[br * 68 + bc * 4] = pb0;
            *(float4*)&Bs[(br + 16) * 68 + bc * 4] = pb1;
        }
        __syncthreads();
        if (kc < 7) {
            pa0 = A4[(mBase + ar) * 64 + (kc + 1) * 8 + ac];
            pa1 = A4[(mBase + ar) * 64 + (kc + 1) * 8 + ac + 4];
            pb0 = B4[((kc + 1) * 32 + br) * 64 + (nBase >> 2) + bc];
            pb1 = B4[((kc + 1) * 32 + br + 16) * 64 + (nBase >> 2) + bc];
        }
        #pragma unroll
        for (int k = 0; k < 32; ++k) {
            float4 a = *(const float4*)&As[k * 68 + ty * 4];
            float4 b = *(const float4*)&Bs[k * 68 + tx * 4];
            float av[4] = {a.x, a.y, a.z, a.w};
            float bv[4] = {b.x, b.y, b.z, b.w};
            #pragma unroll
            for (int i = 0; i < 4; ++i)
                #pragma unroll
                for (int j = 0; j < 4; ++j)
                    acc[i][j] = fmaf(av[i], bv[j], acc[i][j]);
        }
    }

    float4 bias = make_float4(0.f, 0.f, 0.f, 0.f);
    if (which == 0) bias = *((const float4*)b1 + (nBase >> 2) + tx);
    #pragma unroll
    for (int i = 0; i < 4; ++i) {
        float4 o;
        o.x = acc[i][0] + bias.x;
        o.y = acc[i][1] + bias.y;
        o.z = acc[i][2] + bias.z;
        o.w = acc[i][3] + bias.w;
        ((float4*)outp)[(mBase + ty * 4 + i) * (DD / 4) + (nBase >> 2) + tx] = o;
    }
}

// ---------------------------------------------------------------------------
// tanh-form gelu fused with the W2 FMA (7 full-rate + exp2 + rcp = ~30
// cyc/wave-elem).  |err| <= ~5e-4.
//   gelu(h) = h * (1 - 1/(exp2(h*(K1 + K2 h^2)) + 1))
// ---------------------------------------------------------------------------
__device__ __forceinline__ float gelu_term(float xv, float yv, float w, float acc)
{
    float h  = xv + yv;
    float h2 = h * h;
    float z  = h * fmaf(h2, 0.1029432f, 2.3022083f);
    float e  = __builtin_amdgcn_exp2f(z);
    float r  = __builtin_amdgcn_rcpf(e + 1.0f);
    float g  = fmaf(-h, r, h);          // h * (1 - r)
    return fmaf(g, w, acc);
}

// ---------------------------------------------------------------------------
// Kernel 2: o[b,n,m] = sum_d gelu(xp[b,n,d] + yp[b,m,d]) * W2[d] + b2
// 32(n) x 16(m) tile per single-wave block, 4x2 outputs/thread.
// 2048 blocks -> 8 waves/CU -> 2 waves/SIMD (the latency-hiding R2 lacked).
// d staged in chunks of 64; LDS 13 KB/block (8 blocks/CU -> 104 KB).
// Stride-68 rows: all hot-loop ds_read_b128 are conflict-free
// (8 distinct addresses x 8-lane broadcast per instruction).
// ---------------------------------------------------------------------------
__global__ __launch_bounds__(64) void cross_kernel(
    const float* __restrict__ xp, const float* __restrict__ yp,
    const float* __restrict__ W2, const float* __restrict__ b2,
    float* __restrict__ o)
{
    __shared__ float xs[32 * 68];
    __shared__ float ys[16 * 68];

    const int tid   = threadIdx.x;
    const int b     = blockIdx.z;
    const int mBase = blockIdx.x * 16;
    const int nBase = blockIdx.y * 32;
    const int tx = tid & 7;        // m sub-index (cols tx, tx+8)
    const int ty = tid >> 3;       // n sub-index (rows ty+8i)

    const float4* xp4 = (const float4*)xp + (b * N1 + nBase) * (DD / 4);
    const float4* yp4 = (const float4*)yp + (b * N2 + mBase) * (DD / 4);
    const float4* __restrict__ W2v = (const float4*)W2;

    float acc[4][2] = {};

    for (int kc = 0; kc < 4; ++kc) {
        __syncthreads();
        #pragma unroll
        for (int t = 0; t < 8; ++t) {        // xs: 32 rows x 16 float4
            int idx = tid + t * 64;
            int row = idx >> 4;
            int c4  = idx & 15;
            *(float4*)&xs[row * 68 + c4 * 4] = xp4[row * 64 + kc * 16 + c4];
        }
        #pragma unroll
        for (int t = 0; t < 4; ++t) {        // ys: 16 rows x 16 float4
            int idx = tid + t * 64;
            int row = idx >> 4;
            int c4  = idx & 15;
            *(float4*)&ys[row * 68 + c4 * 4] = yp4[row * 64 + kc * 16 + c4];
        }
        __syncthreads();

        #pragma unroll
        for (int c4 = 0; c4 < 16; ++c4) {
            float4 wv = W2v[kc * 16 + c4];   // uniform -> scalar load
            float4 xr[4], yr[2];
            #pragma unroll
            for (int i = 0; i < 4; ++i)
                xr[i] = *(const float4*)&xs[(ty + 8 * i) * 68 + c4 * 4];
            #pragma unroll
            for (int j = 0; j < 2; ++j)
                yr[j] = *(const float4*)&ys[(tx + 8 * j) * 68 + c4 * 4];
            #pragma unroll
            for (int i = 0; i < 4; ++i) {
                #pragma unroll
                for (int j = 0; j < 2; ++j) {
                    float a = acc[i][j];
                    a = gelu_term(xr[i].x, yr[j].x, wv.x, a);
                    a = gelu_term(xr[i].y, yr[j].y, wv.y, a);
                    a = gelu_term(xr[i].z, yr[j].z, wv.z, a);
                    a = gelu_term(xr[i].w, yr[j].w, wv.w, a);
                    acc[i][j] = a;
                }
            }
        }
    }

    const float bias2 = b2[0];
    const size_t base = ((size_t)(b * N1 + nBase)) * N2 + mBase;
    #pragma unroll
    for (int i = 0; i < 4; ++i) {
        #pragma unroll
        for (int j = 0; j < 2; ++j) {
            o[base + (size_t)(ty + 8 * i) * N2 + (tx + 8 * j)] = acc[i][j] + bias2;
        }
    }
}

extern "C" void kernel_launch(void* const* d_in, const int* in_sizes, int n_in,
                              void* d_out, int out_size, void* d_ws, size_t ws_size,
                              hipStream_t stream)
{
    const float* x  = (const float*)d_in[0];
    const float* y  = (const float*)d_in[1];
    const float* W1 = (const float*)d_in[2];
    const float* b1 = (const float*)d_in[3];
    const float* W2 = (const float*)d_in[4];
    const float* b2 = (const float*)d_in[5];
    float* o  = (float*)d_out;
    float* xp = (float*)d_ws;                 // 2048*256 floats = 2 MB
    float* yp = xp + (BB * N1) * DD;          // next 2 MB

    dim3 g1(32, 4, 2);               // (M/64, N/64, which)
    proj_kernel<<<g1, 256, 0, stream>>>(x, y, W1, b1, xp, yp);

    dim3 g2(N2 / 16, N1 / 32, BB);   // 32 x 16 x 4 = 2048 single-wave blocks
    cross_kernel<<<g2, 64, 0, stream>>>(xp, yp, W2, b2, o);
}

// Round 4
// 154.855 us; speedup vs baseline: 1.2685x; 1.0340x over previous
//
#include <hip/hip_runtime.h>

#define DD 256   // feature dim
#define N1 512
#define N2 512
#define BB 4

// ---------------------------------------------------------------------------
// Kernel 1: projection GEMMs (fp32 vector ALU; no fp32 MFMA on CDNA4).
//   which==0: xp = x @ W1[:256]  + b1      (M=2048, N=256, K=256)
//   which==1: yp = y @ W1[256:]            (M=2048, N=256, K=256)
// 32(m) x 64(n) tile / 256 threads / 2x4 register blocking. 512 blocks =
// 2 blocks/CU = 8 waves/CU = 2 waves/SIMD (R3 proj had 1 wave/SIMD).
// K-chunks of 32 with register-prefetch double buffering.
// ---------------------------------------------------------------------------
__global__ __launch_bounds__(256) void proj_kernel(
    const float* __restrict__ x, const float* __restrict__ y,
    const float* __restrict__ W1, const float* __restrict__ b1,
    float* __restrict__ xp, float* __restrict__ yp)
{
    const int which = blockIdx.z;
    const float* __restrict__ A  = which ? y : x;
    const float* __restrict__ Bw = W1 + which * DD * DD;
    float* __restrict__ outp = which ? yp : xp;

    __shared__ float As[32 * 36];   // As[k][m] (transposed), 32 k x 32 m, stride 36
    __shared__ float Bs[32 * 68];   // Bs[k][n], 32 k x 64 n, stride 68

    const int tid = threadIdx.x;
    const int tx = tid & 15, ty = tid >> 4;   // tx: n-group (4 cols), ty: m-group (2 rows)
    const int mBase = blockIdx.x * 32;
    const int nBase = blockIdx.y * 64;

    const float4* A4 = (const float4*)A;
    const float4* B4 = (const float4*)Bw;

    // staging split: A tile 32 rows x 8 float4 = 256 float4 (1/thread)
    //                B tile 32 k-rows x 16 float4 = 512 float4 (2/thread)
    const int ar = tid >> 3;       // 0..31  A row (m)
    const int ac = tid & 7;        // 0..7   A float4 col (k/4)
    const int br = tid >> 4;       // 0..15  B k-row (and +16)
    const int bc = tid & 15;       // 0..15  B float4 col (n/4)

    float4 pa, pb0, pb1;
    pa  = A4[(mBase + ar) * 64 + 0 * 8 + ac];
    pb0 = B4[(0 * 32 + br) * 64 + (nBase >> 2) + bc];
    pb1 = B4[(0 * 32 + br + 16) * 64 + (nBase >> 2) + bc];

    float acc[2][4] = {};

    for (int kc = 0; kc < 8; ++kc) {
        __syncthreads();
        {   // regs -> LDS (A transposed)
            float av[4] = {pa.x, pa.y, pa.z, pa.w};
            #pragma unroll
            for (int q = 0; q < 4; ++q) As[(ac * 4 + q) * 36 + ar] = av[q];
            *(float4*)&Bs[br * 68 + bc * 4] = pb0;
            *(float4*)&Bs[(br + 16) * 68 + bc * 4] = pb1;
        }
        __syncthreads();
        if (kc < 7) {   // prefetch next chunk
            pa  = A4[(mBase + ar) * 64 + (kc + 1) * 8 + ac];
            pb0 = B4[((kc + 1) * 32 + br) * 64 + (nBase >> 2) + bc];
            pb1 = B4[((kc + 1) * 32 + br + 16) * 64 + (nBase >> 2) + bc];
        }
        #pragma unroll
        for (int k = 0; k < 32; ++k) {
            float2 a = *(const float2*)&As[k * 36 + ty * 2];
            float4 b = *(const float4*)&Bs[k * 68 + tx * 4];
            float av[2] = {a.x, a.y};
            float bv[4] = {b.x, b.y, b.z, b.w};
            #pragma unroll
            for (int i = 0; i < 2; ++i)
                #pragma unroll
                for (int j = 0; j < 4; ++j)
                    acc[i][j] = fmaf(av[i], bv[j], acc[i][j]);
        }
    }

    float4 bias = make_float4(0.f, 0.f, 0.f, 0.f);
    if (which == 0) bias = *((const float4*)b1 + (nBase >> 2) + tx);
    #pragma unroll
    for (int i = 0; i < 2; ++i) {
        float4 o;
        o.x = acc[i][0] + bias.x;
        o.y = acc[i][1] + bias.y;
        o.z = acc[i][2] + bias.z;
        o.w = acc[i][3] + bias.w;
        ((float4*)outp)[(mBase + ty * 2 + i) * (DD / 4) + (nBase >> 2) + tx] = o;
    }
}

// ---------------------------------------------------------------------------
// tanh-form gelu fused with the W2 FMA (7 full-rate + exp2 + rcp = ~30
// cyc/wave-elem).  |err| <= ~5e-4.
//   gelu(h) = h * (1 - 1/(exp2(h*(K1 + K2 h^2)) + 1))
// ---------------------------------------------------------------------------
__device__ __forceinline__ float gelu_term(float xv, float yv, float w, float acc)
{
    float h  = xv + yv;
    float h2 = h * h;
    float z  = h * fmaf(h2, 0.1029432f, 2.3022083f);
    float e  = __builtin_amdgcn_exp2f(z);
    float r  = __builtin_amdgcn_rcpf(e + 1.0f);
    float g  = fmaf(-h, r, h);          // h * (1 - r)
    return fmaf(g, w, acc);
}

// ---------------------------------------------------------------------------
// Kernel 2: o[b,n,m] = sum_d gelu(xp[b,n,d] + yp[b,m,d]) * W2[d] + b2
// 16(n) x 16(m) tile per single-wave block, 2x2 outputs/thread.
// 4096 blocks -> 16 waves/CU -> 4 waves/SIMD (covers exp2/rcp latency that
// left 31% of issue slots idle at 2 waves/SIMD in R3).
// d staged in chunks of 64; LDS 8.5 KB/block (16 blocks/CU -> 136 KB).
// Stride-68 rows keep all hot-loop ds_read_b128 conflict-free.
// ---------------------------------------------------------------------------
__global__ __launch_bounds__(64) void cross_kernel(
    const float* __restrict__ xp, const float* __restrict__ yp,
    const float* __restrict__ W2, const float* __restrict__ b2,
    float* __restrict__ o)
{
    __shared__ float xs[16 * 68];
    __shared__ float ys[16 * 68];

    const int tid   = threadIdx.x;
    const int b     = blockIdx.z;
    const int mBase = blockIdx.x * 16;
    const int nBase = blockIdx.y * 16;
    const int tx = tid & 7;        // m sub-index (cols tx, tx+8)
    const int ty = tid >> 3;       // n sub-index (rows ty, ty+8)

    const float4* xp4 = (const float4*)xp + (b * N1 + nBase) * (DD / 4);
    const float4* yp4 = (const float4*)yp + (b * N2 + mBase) * (DD / 4);
    const float4* __restrict__ W2v = (const float4*)W2;

    float acc[2][2] = {};

    for (int kc = 0; kc < 4; ++kc) {
        __syncthreads();
        #pragma unroll
        for (int t = 0; t < 4; ++t) {        // xs: 16 rows x 16 float4
            int idx = tid + t * 64;          // 0..255
            int row = idx >> 4;              // 0..15
            int c4  = idx & 15;
            *(float4*)&xs[row * 68 + c4 * 4] = xp4[row * 64 + kc * 16 + c4];
        }
        #pragma unroll
        for (int t = 0; t < 4; ++t) {        // ys: 16 rows x 16 float4
            int idx = tid + t * 64;
            int row = idx >> 4;
            int c4  = idx & 15;
            *(float4*)&ys[row * 68 + c4 * 4] = yp4[row * 64 + kc * 16 + c4];
        }
        __syncthreads();

        #pragma unroll
        for (int c4 = 0; c4 < 16; ++c4) {
            float4 wv = W2v[kc * 16 + c4];   // uniform -> scalar load
            float4 xr[2], yr[2];
            #pragma unroll
            for (int i = 0; i < 2; ++i)
                xr[i] = *(const float4*)&xs[(ty + 8 * i) * 68 + c4 * 4];
            #pragma unroll
            for (int j = 0; j < 2; ++j)
                yr[j] = *(const float4*)&ys[(tx + 8 * j) * 68 + c4 * 4];
            #pragma unroll
            for (int i = 0; i < 2; ++i) {
                #pragma unroll
                for (int j = 0; j < 2; ++j) {
                    float a = acc[i][j];
                    a = gelu_term(xr[i].x, yr[j].x, wv.x, a);
                    a = gelu_term(xr[i].y, yr[j].y, wv.y, a);
                    a = gelu_term(xr[i].z, yr[j].z, wv.z, a);
                    a = gelu_term(xr[i].w, yr[j].w, wv.w, a);
                    acc[i][j] = a;
                }
            }
        }
    }

    const float bias2 = b2[0];
    const size_t base = ((size_t)(b * N1 + nBase)) * N2 + mBase;
    #pragma unroll
    for (int i = 0; i < 2; ++i) {
        #pragma unroll
        for (int j = 0; j < 2; ++j) {
            o[base + (size_t)(ty + 8 * i) * N2 + (tx + 8 * j)] = acc[i][j] + bias2;
        }
    }
}

extern "C" void kernel_launch(void* const* d_in, const int* in_sizes, int n_in,
                              void* d_out, int out_size, void* d_ws, size_t ws_size,
                              hipStream_t stream)
{
    const float* x  = (const float*)d_in[0];
    const float* y  = (const float*)d_in[1];
    const float* W1 = (const float*)d_in[2];
    const float* b1 = (const float*)d_in[3];
    const float* W2 = (const float*)d_in[4];
    const float* b2 = (const float*)d_in[5];
    float* o  = (float*)d_out;
    float* xp = (float*)d_ws;                 // 2048*256 floats = 2 MB
    float* yp = xp + (BB * N1) * DD;          // next 2 MB

    dim3 g1(64, 4, 2);               // (M/32, N/64, which) = 512 blocks
    proj_kernel<<<g1, 256, 0, stream>>>(x, y, W1, b1, xp, yp);

    dim3 g2(N2 / 16, N1 / 16, BB);   // 32 x 32 x 4 = 4096 single-wave blocks
    cross_kernel<<<g2, 64, 0, stream>>>(xp, yp, W2, b2, o);
}

// Round 6
// 149.598 us; speedup vs baseline: 1.3131x; 1.0351x over previous
//
#include <hip/hip_runtime.h>

#define DD 256   // feature dim
#define N1 512
#define N2 512
#define BB 4

// Packed fp32: gfx950 (gfx90a+) has PackedFP32Ops; the compiler selects
// v_pk_{add,mul,fma}_f32 from <2 x float> vector IR. Using vector arithmetic
// + __builtin_elementwise_fma keeps semantics exact (R5's hand-rolled VOP3P
// inline asm silently produced garbage — never again).
typedef float f2 __attribute__((ext_vector_type(2)));

// ---------------------------------------------------------------------------
// Kernel 1: projection GEMMs (fp32 vector ALU; no fp32 MFMA on CDNA4).
// 32(m) x 64(n) tile / 256 threads / 2x4 register blocking, K-chunks of 32,
// register-prefetch double buffering. 512 blocks = 2 blocks/CU.
// ---------------------------------------------------------------------------
__global__ __launch_bounds__(256) void proj_kernel(
    const float* __restrict__ x, const float* __restrict__ y,
    const float* __restrict__ W1, const float* __restrict__ b1,
    float* __restrict__ xp, float* __restrict__ yp)
{
    const int which = blockIdx.z;
    const float* __restrict__ A  = which ? y : x;
    const float* __restrict__ Bw = W1 + which * DD * DD;
    float* __restrict__ outp = which ? yp : xp;

    __shared__ float As[32 * 36];   // As[k][m] (transposed), stride 36
    __shared__ float Bs[32 * 68];   // Bs[k][n], stride 68

    const int tid = threadIdx.x;
    const int tx = tid & 15, ty = tid >> 4;
    const int mBase = blockIdx.x * 32;
    const int nBase = blockIdx.y * 64;

    const float4* A4 = (const float4*)A;
    const float4* B4 = (const float4*)Bw;

    const int ar = tid >> 3;       // 0..31  A row (m)
    const int ac = tid & 7;        // 0..7   A float4 col (k/4)
    const int br = tid >> 4;       // 0..15  B k-row (and +16)
    const int bc = tid & 15;       // 0..15  B float4 col (n/4)

    float4 pa, pb0, pb1;
    pa  = A4[(mBase + ar) * 64 + 0 * 8 + ac];
    pb0 = B4[(0 * 32 + br) * 64 + (nBase >> 2) + bc];
    pb1 = B4[(0 * 32 + br + 16) * 64 + (nBase >> 2) + bc];

    float acc[2][4] = {};

    for (int kc = 0; kc < 8; ++kc) {
        __syncthreads();
        {
            float av[4] = {pa.x, pa.y, pa.z, pa.w};
            #pragma unroll
            for (int q = 0; q < 4; ++q) As[(ac * 4 + q) * 36 + ar] = av[q];
            *(float4*)&Bs[br * 68 + bc * 4] = pb0;
            *(float4*)&Bs[(br + 16) * 68 + bc * 4] = pb1;
        }
        __syncthreads();
        if (kc < 7) {
            pa  = A4[(mBase + ar) * 64 + (kc + 1) * 8 + ac];
            pb0 = B4[((kc + 1) * 32 + br) * 64 + (nBase >> 2) + bc];
            pb1 = B4[((kc + 1) * 32 + br + 16) * 64 + (nBase >> 2) + bc];
        }
        #pragma unroll
        for (int k = 0; k < 32; ++k) {
            float2 a = *(const float2*)&As[k * 36 + ty * 2];
            float4 b = *(const float4*)&Bs[k * 68 + tx * 4];
            float av[2] = {a.x, a.y};
            float bv[4] = {b.x, b.y, b.z, b.w};
            #pragma unroll
            for (int i = 0; i < 2; ++i)
                #pragma unroll
                for (int j = 0; j < 4; ++j)
                    acc[i][j] = fmaf(av[i], bv[j], acc[i][j]);
        }
    }

    float4 bias = make_float4(0.f, 0.f, 0.f, 0.f);
    if (which == 0) bias = *((const float4*)b1 + (nBase >> 2) + tx);
    #pragma unroll
    for (int i = 0; i < 2; ++i) {
        float4 o;
        o.x = acc[i][0] + bias.x;
        o.y = acc[i][1] + bias.y;
        o.z = acc[i][2] + bias.z;
        o.w = acc[i][3] + bias.w;
        ((float4*)outp)[(mBase + ty * 2 + i) * (DD / 4) + (nBase >> 2) + tx] = o;
    }
}

// ---------------------------------------------------------------------------
// Packed tanh-form gelu pair (same math as the R2-R4 scalar version that
// passed at absmax 3.9e-3):
//   gelu(h) = h * (1 - 1/(exp2(h*(K1 + K2 h^2)) + 1))
// Vector ops -> v_pk_*_f32 where the backend packs; exp2/rcp stay scalar
// (one trans op per element either way).
// ---------------------------------------------------------------------------
__device__ __forceinline__ f2 gelu2(f2 h)
{
    f2 h2 = h * h;
    f2 t  = __builtin_elementwise_fma(h2, (f2)0.1029432f, (f2)2.3022083f);
    f2 z  = h * t;
    f2 e;
    e.x = __builtin_amdgcn_exp2f(z.x);
    e.y = __builtin_amdgcn_exp2f(z.y);
    f2 a = e + 1.0f;
    f2 r;
    r.x = __builtin_amdgcn_rcpf(a.x);
    r.y = __builtin_amdgcn_rcpf(a.y);
    return __builtin_elementwise_fma(-h, r, h);   // h - h*r = h*sigmoid(z)
}

// ---------------------------------------------------------------------------
// Kernel 2: o[b,n,m] = sum_d gelu(xp[b,n,d] + yp[b,m,d]) * W2[d] + b2
// 16x16 tile per single-wave block, 2x2 outputs/thread, packed-f32 math.
// Register double-buffered staging (8 float4/thread prefetch) hides global
// latency; single-wave blocks make __syncthreads ~free.
// 4096 blocks -> 16 waves/CU -> 4 waves/SIMD. Stride-68 LDS rows keep all
// hot-loop ds_read_b128 conflict-free.
// ---------------------------------------------------------------------------
__global__ __launch_bounds__(64, 4) void cross_kernel(
    const float* __restrict__ xp, const float* __restrict__ yp,
    const float* __restrict__ W2, const float* __restrict__ b2,
    float* __restrict__ o)
{
    __shared__ float xs[16 * 68];
    __shared__ float ys[16 * 68];

    const int tid   = threadIdx.x;
    const int b     = blockIdx.z;
    const int mBase = blockIdx.x * 16;
    const int nBase = blockIdx.y * 16;
    const int tx = tid & 7;        // m sub-index (cols tx, tx+8)
    const int ty = tid >> 3;       // n sub-index (rows ty, ty+8)

    const float4* xp4 = (const float4*)xp + (b * N1 + nBase) * (DD / 4);
    const float4* yp4 = (const float4*)yp + (b * N2 + mBase) * (DD / 4);
    const float4* __restrict__ W2v = (const float4*)W2;

    // staging geometry: 4 float4 per thread per panel per chunk
    const int srow = tid >> 4;          // 0..3 base row
    const int sc4  = tid & 15;          // float4 col

    float4 px[4], py[4];
    #pragma unroll
    for (int t = 0; t < 4; ++t) {
        int row = srow + 4 * t;
        px[t] = xp4[row * 64 + 0 * 16 + sc4];
        py[t] = yp4[row * 64 + 0 * 16 + sc4];
    }

    f2 acc[2][2] = {};

    for (int kc = 0; kc < 4; ++kc) {
        __syncthreads();
        #pragma unroll
        for (int t = 0; t < 4; ++t) {
            int row = srow + 4 * t;
            *(float4*)&xs[row * 68 + sc4 * 4] = px[t];
            *(float4*)&ys[row * 68 + sc4 * 4] = py[t];
        }
        __syncthreads();
        if (kc < 3) {
            #pragma unroll
            for (int t = 0; t < 4; ++t) {
                int row = srow + 4 * t;
                px[t] = xp4[row * 64 + (kc + 1) * 16 + sc4];
                py[t] = yp4[row * 64 + (kc + 1) * 16 + sc4];
            }
        }

        #pragma unroll
        for (int c4 = 0; c4 < 16; ++c4) {
            float4 wv = W2v[kc * 16 + c4];   // uniform -> scalar load
            f2 wlo = {wv.x, wv.y};
            f2 whi = {wv.z, wv.w};
            float4 xr[2], yr[2];
            #pragma unroll
            for (int i = 0; i < 2; ++i)
                xr[i] = *(const float4*)&xs[(ty + 8 * i) * 68 + c4 * 4];
            #pragma unroll
            for (int j = 0; j < 2; ++j)
                yr[j] = *(const float4*)&ys[(tx + 8 * j) * 68 + c4 * 4];
            #pragma unroll
            for (int i = 0; i < 2; ++i) {
                f2 xlo = {xr[i].x, xr[i].y};
                f2 xhi = {xr[i].z, xr[i].w};
                #pragma unroll
                for (int j = 0; j < 2; ++j) {
                    f2 ylo = {yr[j].x, yr[j].y};
                    f2 yhi = {yr[j].z, yr[j].w};
                    f2 glo = gelu2(xlo + ylo);
                    acc[i][j] = __builtin_elementwise_fma(glo, wlo, acc[i][j]);
                    f2 ghi = gelu2(xhi + yhi);
                    acc[i][j] = __builtin_elementwise_fma(ghi, whi, acc[i][j]);
                }
            }
        }
    }

    const float bias2 = b2[0];
    const size_t base = ((size_t)(b * N1 + nBase)) * N2 + mBase;
    #pragma unroll
    for (int i = 0; i < 2; ++i) {
        #pragma unroll
        for (int j = 0; j < 2; ++j) {
            o[base + (size_t)(ty + 8 * i) * N2 + (tx + 8 * j)] =
                acc[i][j].x + acc[i][j].y + bias2;
        }
    }
}

extern "C" void kernel_launch(void* const* d_in, const int* in_sizes, int n_in,
                              void* d_out, int out_size, void* d_ws, size_t ws_size,
                              hipStream_t stream)
{
    const float* x  = (const float*)d_in[0];
    const float* y  = (const float*)d_in[1];
    const float* W1 = (const float*)d_in[2];
    const float* b1 = (const float*)d_in[3];
    const float* W2 = (const float*)d_in[4];
    const float* b2 = (const float*)d_in[5];
    float* o  = (float*)d_out;
    float* xp = (float*)d_ws;                 // 2048*256 floats = 2 MB
    float* yp = xp + (BB * N1) * DD;          // next 2 MB

    dim3 g1(64, 4, 2);               // (M/32, N/64, which) = 512 blocks
    proj_kernel<<<g1, 256, 0, stream>>>(x, y, W1, b1, xp, yp);

    dim3 g2(N2 / 16, N1 / 16, BB);   // 32 x 32 x 4 = 4096 single-wave blocks
    cross_kernel<<<g2, 64, 0, stream>>>(xp, yp, W2, b2, o);
}

// Round 7
// 141.990 us; speedup vs baseline: 1.3835x; 1.0536x over previous
//
#include <hip/hip_runtime.h>

#define DD 256   // feature dim
#define N1 512
#define N2 512
#define BB 4

// Packed fp32: gfx950 (gfx90a+) PackedFP32Ops; the compiler selects
// v_pk_{add,mul,fma}_f32 from <2 x float> vector IR. (R5's hand-rolled VOP3P
// inline asm silently produced garbage — vector IR is the safe route.)
typedef float f2 __attribute__((ext_vector_type(2)));

// ---------------------------------------------------------------------------
// Kernel 1: projection GEMMs (fp32 vector ALU; no fp32 MFMA on CDNA4).
// 32(m) x 64(n) tile / 256 threads / 2x4 register blocking, K-chunks of 32,
// register-prefetch double buffering. 512 blocks = 2 blocks/CU.
// ---------------------------------------------------------------------------
__global__ __launch_bounds__(256) void proj_kernel(
    const float* __restrict__ x, const float* __restrict__ y,
    const float* __restrict__ W1, const float* __restrict__ b1,
    float* __restrict__ xp, float* __restrict__ yp)
{
    const int which = blockIdx.z;
    const float* __restrict__ A  = which ? y : x;
    const float* __restrict__ Bw = W1 + which * DD * DD;
    float* __restrict__ outp = which ? yp : xp;

    __shared__ float As[32 * 36];   // As[k][m] (transposed), stride 36
    __shared__ float Bs[32 * 68];   // Bs[k][n], stride 68

    const int tid = threadIdx.x;
    const int tx = tid & 15, ty = tid >> 4;
    const int mBase = blockIdx.x * 32;
    const int nBase = blockIdx.y * 64;

    const float4* A4 = (const float4*)A;
    const float4* B4 = (const float4*)Bw;

    const int ar = tid >> 3;       // 0..31  A row (m)
    const int ac = tid & 7;        // 0..7   A float4 col (k/4)
    const int br = tid >> 4;       // 0..15  B k-row (and +16)
    const int bc = tid & 15;       // 0..15  B float4 col (n/4)

    float4 pa, pb0, pb1;
    pa  = A4[(mBase + ar) * 64 + 0 * 8 + ac];
    pb0 = B4[(0 * 32 + br) * 64 + (nBase >> 2) + bc];
    pb1 = B4[(0 * 32 + br + 16) * 64 + (nBase >> 2) + bc];

    float acc[2][4] = {};

    for (int kc = 0; kc < 8; ++kc) {
        __syncthreads();
        {
            float av[4] = {pa.x, pa.y, pa.z, pa.w};
            #pragma unroll
            for (int q = 0; q < 4; ++q) As[(ac * 4 + q) * 36 + ar] = av[q];
            *(float4*)&Bs[br * 68 + bc * 4] = pb0;
            *(float4*)&Bs[(br + 16) * 68 + bc * 4] = pb1;
        }
        __syncthreads();
        if (kc < 7) {
            pa  = A4[(mBase + ar) * 64 + (kc + 1) * 8 + ac];
            pb0 = B4[((kc + 1) * 32 + br) * 64 + (nBase >> 2) + bc];
            pb1 = B4[((kc + 1) * 32 + br + 16) * 64 + (nBase >> 2) + bc];
        }
        #pragma unroll
        for (int k = 0; k < 32; ++k) {
            float2 a = *(const float2*)&As[k * 36 + ty * 2];
            float4 b = *(const float4*)&Bs[k * 68 + tx * 4];
            float av[2] = {a.x, a.y};
            float bv[4] = {b.x, b.y, b.z, b.w};
            #pragma unroll
            for (int i = 0; i < 2; ++i)
                #pragma unroll
                for (int j = 0; j < 4; ++j)
                    acc[i][j] = fmaf(av[i], bv[j], acc[i][j]);
        }
    }

    float4 bias = make_float4(0.f, 0.f, 0.f, 0.f);
    if (which == 0) bias = *((const float4*)b1 + (nBase >> 2) + tx);
    #pragma unroll
    for (int i = 0; i < 2; ++i) {
        float4 o;
        o.x = acc[i][0] + bias.x;
        o.y = acc[i][1] + bias.y;
        o.z = acc[i][2] + bias.z;
        o.w = acc[i][3] + bias.w;
        ((float4*)outp)[(mBase + ty * 2 + i) * (DD / 4) + (nBase >> 2) + tx] = o;
    }
}

// ---------------------------------------------------------------------------
// Packed tanh-form gelu pair (same math as R2-R6, absmax 3.9e-3):
//   gelu(h) = h * (1 - 1/(exp2(h*(K1 + K2 h^2)) + 1))
// ---------------------------------------------------------------------------
__device__ __forceinline__ f2 gelu2(f2 h)
{
    f2 h2 = h * h;
    f2 t  = __builtin_elementwise_fma(h2, (f2)0.1029432f, (f2)2.3022083f);
    f2 z  = h * t;
    f2 e;
    e.x = __builtin_amdgcn_exp2f(z.x);
    e.y = __builtin_amdgcn_exp2f(z.y);
    f2 a = e + 1.0f;
    f2 r;
    r.x = __builtin_amdgcn_rcpf(a.x);
    r.y = __builtin_amdgcn_rcpf(a.y);
    return __builtin_elementwise_fma(-h, r, h);   // h - h*r = h*sigmoid(z)
}

// ---------------------------------------------------------------------------
// Kernel 2: o[b,n,m] = sum_d gelu(xp[b,n,d] + yp[b,m,d]) * W2[d] + b2
// 32x32 tile per 256-thread (4-wave) block, 2x2 outputs/thread.
// 1024 blocks = 4 blocks/CU x 4 waves = 16 waves/CU resident (fixes the
// workgroup-slot cap that left R6 at ~9 waves/CU), and 2x the data reuse
// (64 KB global reads per 1024 outputs) halving L2 traffic.
// d staged in chunks of 64 with register double-buffering. Stride-68 LDS
// rows: xr reads are 16-lane broadcast; yr reads 2-way aliased (free).
// ---------------------------------------------------------------------------
__global__ __launch_bounds__(256, 4) void cross_kernel(
    const float* __restrict__ xp, const float* __restrict__ yp,
    const float* __restrict__ W2, const float* __restrict__ b2,
    float* __restrict__ o)
{
    __shared__ float xs[32 * 68];
    __shared__ float ys[32 * 68];

    const int tid   = threadIdx.x;
    const int b     = blockIdx.z;
    const int mBase = blockIdx.x * 32;
    const int nBase = blockIdx.y * 32;
    const int tx = tid & 15;       // m sub-index (cols tx, tx+16)
    const int ty = tid >> 4;       // n sub-index (rows ty, ty+16)

    const float4* xp4 = (const float4*)xp + (b * N1 + nBase) * (DD / 4);
    const float4* yp4 = (const float4*)yp + (b * N2 + mBase) * (DD / 4);
    const float4* __restrict__ W2v = (const float4*)W2;

    // staging: 2 float4 per thread per panel per chunk (rows srow, srow+16)
    const int srow = tid >> 4;          // 0..15
    const int sc4  = tid & 15;          // float4 col within chunk

    float4 px[2], py[2];
    px[0] = xp4[srow * 64 + 0 * 16 + sc4];
    px[1] = xp4[(srow + 16) * 64 + 0 * 16 + sc4];
    py[0] = yp4[srow * 64 + 0 * 16 + sc4];
    py[1] = yp4[(srow + 16) * 64 + 0 * 16 + sc4];

    f2 acc[2][2] = {};

    for (int kc = 0; kc < 4; ++kc) {
        __syncthreads();
        *(float4*)&xs[srow * 68 + sc4 * 4]        = px[0];
        *(float4*)&xs[(srow + 16) * 68 + sc4 * 4] = px[1];
        *(float4*)&ys[srow * 68 + sc4 * 4]        = py[0];
        *(float4*)&ys[(srow + 16) * 68 + sc4 * 4] = py[1];
        __syncthreads();
        if (kc < 3) {
            px[0] = xp4[srow * 64 + (kc + 1) * 16 + sc4];
            px[1] = xp4[(srow + 16) * 64 + (kc + 1) * 16 + sc4];
            py[0] = yp4[srow * 64 + (kc + 1) * 16 + sc4];
            py[1] = yp4[(srow + 16) * 64 + (kc + 1) * 16 + sc4];
        }

        #pragma unroll
        for (int c4 = 0; c4 < 16; ++c4) {
            float4 wv = W2v[kc * 16 + c4];   // uniform -> scalar load
            f2 wlo = {wv.x, wv.y};
            f2 whi = {wv.z, wv.w};
            float4 xr[2], yr[2];
            #pragma unroll
            for (int i = 0; i < 2; ++i)
                xr[i] = *(const float4*)&xs[(ty + 16 * i) * 68 + c4 * 4];
            #pragma unroll
            for (int j = 0; j < 2; ++j)
                yr[j] = *(const float4*)&ys[(tx + 16 * j) * 68 + c4 * 4];
            #pragma unroll
            for (int i = 0; i < 2; ++i) {
                f2 xlo = {xr[i].x, xr[i].y};
                f2 xhi = {xr[i].z, xr[i].w};
                #pragma unroll
                for (int j = 0; j < 2; ++j) {
                    f2 ylo = {yr[j].x, yr[j].y};
                    f2 yhi = {yr[j].z, yr[j].w};
                    f2 glo = gelu2(xlo + ylo);
                    acc[i][j] = __builtin_elementwise_fma(glo, wlo, acc[i][j]);
                    f2 ghi = gelu2(xhi + yhi);
                    acc[i][j] = __builtin_elementwise_fma(ghi, whi, acc[i][j]);
                }
            }
        }
    }

    const float bias2 = b2[0];
    const size_t base = ((size_t)(b * N1 + nBase)) * N2 + mBase;
    #pragma unroll
    for (int i = 0; i < 2; ++i) {
        #pragma unroll
        for (int j = 0; j < 2; ++j) {
            o[base + (size_t)(ty + 16 * i) * N2 + (tx + 16 * j)] =
                acc[i][j].x + acc[i][j].y + bias2;
        }
    }
}

extern "C" void kernel_launch(void* const* d_in, const int* in_sizes, int n_in,
                              void* d_out, int out_size, void* d_ws, size_t ws_size,
                              hipStream_t stream)
{
    const float* x  = (const float*)d_in[0];
    const float* y  = (const float*)d_in[1];
    const float* W1 = (const float*)d_in[2];
    const float* b1 = (const float*)d_in[3];
    const float* W2 = (const float*)d_in[4];
    const float* b2 = (const float*)d_in[5];
    float* o  = (float*)d_out;
    float* xp = (float*)d_ws;                 // 2048*256 floats = 2 MB
    float* yp = xp + (BB * N1) * DD;          // next 2 MB

    dim3 g1(64, 4, 2);               // (M/32, N/64, which) = 512 blocks
    proj_kernel<<<g1, 256, 0, stream>>>(x, y, W1, b1, xp, yp);

    dim3 g2(N2 / 32, N1 / 32, BB);   // 16 x 16 x 4 = 1024 four-wave blocks
    cross_kernel<<<g2, 256, 0, stream>>>(xp, yp, W2, b2, o);
}